// Round 3
// baseline (300.416 us; speedup 1.0000x reference)
//
#include <hip/hip_runtime.h>
#include <hip/hip_bf16.h>

typedef unsigned short u16;
typedef __bf16 bf16x8 __attribute__((ext_vector_type(8)));
typedef float floatx4 __attribute__((ext_vector_type(4)));
typedef __hip_bfloat16 bf;

__device__ __forceinline__ __bf16 f2b(float f) {
    __hip_bfloat16 h = __float2bfloat16(f);
    return *reinterpret_cast<__bf16*>(&h);
}
__device__ __forceinline__ bf16x8 ld8f(const float* p) {
    float4 a = ((const float4*)p)[0];
    float4 b = ((const float4*)p)[1];
    bf16x8 r;
    r[0] = f2b(a.x); r[1] = f2b(a.y); r[2] = f2b(a.z); r[3] = f2b(a.w);
    r[4] = f2b(b.x); r[5] = f2b(b.y); r[6] = f2b(b.z); r[7] = f2b(b.w);
    return r;
}
__device__ __forceinline__ void storev(float* p, float v) { *p = v; }
__device__ __forceinline__ void storev(bf* p, float v)    { *p = __float2bfloat16(v); }

// async 16-B global->LDS (dest = wave-uniform base + lane*16; our dest map
// tid*16 conforms: wave*1024 + lane*16)
__device__ __forceinline__ void gl16(const bf* g, u16* l) {
    __builtin_amdgcn_global_load_lds(
        (const __attribute__((address_space(1))) void*)g,
        (__attribute__((address_space(3))) void*)l, 16, 0, 0);
}

// ============================================================================
// 4-phase NT GEMM: C[m,n] = scale * sum_k A[m,k]*B[n,k]
// Tile BM=128 x BN=256, BK=64 (K-tile). 512 thr = 8 waves (2M x 4N), per-wave
// output 64x64 = 4x4 16x16 frags. LDS 96 KiB: 2 K-tile buffers, each
// {A: [128][64], B: 2 regions x [128][64]}, region-major (linear gl16 dest).
//
// R2 lesson: 8 MFMA/phase left per-phase fixed cost (2 barriers + lgkm drain
// + stage issue ~650 cyc) at 2/3 of each phase -> MfmaUtil 26%.  This version
// runs 2 phases per K-tile, 16 MFMA each (m201's per-phase MFMA count) with
// the same proven swizzle/addressing.
//
// Phase schedule (iteration = K-tiles t=2it, t+1):
//   ph1: rd buf0 A0,A1,B0 (12 ds)  | stage[if it] buf1.{B0u1,B1u0,B1u1}(t+1)
//        | BAR lgkm0 | QMM(A0,B0)+QMM(A1,B0) | BAR
//   ph2: rd buf0 B1 (4 ds)         | stage buf0.{A0,A1,B0u0}(t+2)
//        | BAR lgkm0 | QMM(A0,B1)+QMM(A1,B1) | vmcnt(3) BAR
//   ph3: rd buf1 A0,A1,B0          | stage buf0.{B0u1,B1u0,B1u1}(t+2)
//        | BAR lgkm0 | 16 MFMA | BAR
//   ph4: rd buf1 B1                | stage buf1.{A0,A1,B0u0}(t+3)
//        | BAR lgkm0 | 16 MFMA | vmcnt(3) BAR
// Hazards: every region staged >= 1 phase after its last read (reads of a
// region end at that phase's lgkm0; staging issues only after the NEXT
// barrier).  vmcnt(3) at ph2-end drains ph4-prev + ph1-cur (all of buf1's
// tile t+1) before ph3 reads it; vmcnt(3) at ph4-end drains ph2+ph3 (buf0's
// tile t+2) before next-ph1.  Steady state 3-9 loads in flight, never 0.
// Iter 0: ph1 stage skipped (prologue staged tiles 0,1 and drained vmcnt(0)).
// LDS k-swizzle: LDS(row, kl) holds X[grow][kl ^ ((row&7)<<3)] — applied on
// the pre-swizzled GLOBAL source (gl16 dest linear) and on ds_read (R2:
// SQ_LDS_BANK_CONFLICT = 0).  Requires K % 128 == 0 (K in {1024, 2048}).
// ============================================================================

#define FENCE asm volatile("" ::: "memory")
#define BARx  __builtin_amdgcn_s_barrier()
#define LGKM0 asm volatile("s_waitcnt lgkmcnt(0)" ::: "memory")
#define VM3   asm volatile("s_waitcnt vmcnt(3)" ::: "memory")
#define VM0   asm volatile("s_waitcnt vmcnt(0)" ::: "memory")

#define ST_A(h, kt, Ab) \
    gl16(Asrc + (long)((h) * 32) * K + (long)(kt) * 64, (Ab) + (h) * 4096 + tid * 8)
#define ST_Bu0(c, kt, Bb) \
    gl16(Bsrc + (long)((c) * 32) * K + (long)(kt) * 64, (Bb) + (c) * 8192 + tid * 8)
#define ST_Bu1(c, kt, Bb) \
    gl16(Bsrc + (long)((c) * 32 + 128) * K + (long)(kt) * 64, (Bb) + (c) * 8192 + 4096 + tid * 8)

#define RD_A(dst, h, Ab) do { _Pragma("unroll") \
    for (int q_ = 0; q_ < 2; q_++) { \
        const u16* p_ = (Ab) + ((h) * 64 + wg * 32 + q_ * 16 + fr) * 64; \
        dst[q_ * 2 + 0] = *(const bf16x8*)(p_ + kl0); \
        dst[q_ * 2 + 1] = *(const bf16x8*)(p_ + kl1); \
    } } while (0)

#define RD_B(dst, c, Bb) do { _Pragma("unroll") \
    for (int j_ = 0; j_ < 2; j_++) { \
        const u16* p_ = (Bb) + ((c) * 128 + w4 * 32 + j_ * 16 + fr) * 64; \
        dst[j_ * 2 + 0] = *(const bf16x8*)(p_ + kl0); \
        dst[j_ * 2 + 1] = *(const bf16x8*)(p_ + kl1); \
    } } while (0)

#define QMM(h, c, av, bv) do { _Pragma("unroll") \
    for (int q_ = 0; q_ < 2; q_++) _Pragma("unroll") \
    for (int j_ = 0; j_ < 2; j_++) _Pragma("unroll") \
    for (int kk_ = 0; kk_ < 2; kk_++) \
        acc[(h) * 2 + q_][(c) * 2 + j_] = __builtin_amdgcn_mfma_f32_16x16x32_bf16( \
            av[q_ * 2 + kk_], bv[j_ * 2 + kk_], acc[(h) * 2 + q_][(c) * 2 + j_], 0, 0, 0); \
} while (0)

template <typename OutT>
__device__ __forceinline__ void gemm8_core(
    const bf* __restrict__ A, const bf* __restrict__ B, OutT* __restrict__ C,
    int K, int N, int m_blk, int n_blk, float scale, u16* lds)
{
    const int tid  = threadIdx.x;
    const int w    = tid >> 6, lane = tid & 63;
    const int wg   = w >> 2, w4 = w & 3;          // wave grid 2M x 4N
    const int fr   = lane & 15, kg = lane >> 4;

    // LDS geometry (elems): buf0 {A:8192, B:16384}, buf1 likewise
    u16* const A0b = lds;
    u16* const B0b = lds + 8192;
    u16* const A1b = lds + 24576;
    u16* const B1b = lds + 32768;

    // read-side swizzled k offsets (kl1 = kl0 ^ 32 holds under the swizzle)
    const int kl0 = (kg * 8) ^ ((fr & 7) << 3);
    const int kl1 = kl0 ^ 32;

    // staging constants: thread t covers LDS row (t>>3), 16B chunk (t&7);
    // source col pre-swizzled with the same involution keyed on row&7
    const int sr  = tid >> 3;                      // 0..63
    const int scs = ((tid & 7) * 8) ^ ((sr & 7) << 3);
    const bf* Asrc = A + (long)(m_blk + (tid >> 8) * 64 + (sr & 31)) * K + scs;
    const bf* Bsrc = B + (long)(n_blk + (tid >> 8) * 64 + (sr & 31)) * K + scs;

    floatx4 acc[4][4];
#pragma unroll
    for (int i = 0; i < 4; i++)
#pragma unroll
        for (int j = 0; j < 4; j++) acc[i][j] = (floatx4){0.f, 0.f, 0.f, 0.f};

    bf16x8 a0[4], a1[4], b0[4], b1[4];

    const int T     = K >> 6;    // K-tiles, even
    const int iters = T >> 1;

    // prologue: stage tiles 0 -> buf0, 1 -> buf1 fully; drain
    ST_A(0, 0, A0b); ST_A(1, 0, A0b);
    ST_Bu0(0, 0, B0b); ST_Bu1(0, 0, B0b); ST_Bu0(1, 0, B0b); ST_Bu1(1, 0, B0b);
    ST_A(0, 1, A1b); ST_A(1, 1, A1b);
    ST_Bu0(0, 1, B1b); ST_Bu1(0, 1, B1b); ST_Bu0(1, 1, B1b); ST_Bu1(1, 1, B1b);
    VM0; BARx;

    for (int it = 0; it < iters; ++it) {
        const int t   = it * 2;
        const int ts0 = (t + 2 < T) ? t + 2 : 0;   // clamped: data unused
        const int ts1 = (t + 3 < T) ? t + 3 : 0;

        // ph1: rd buf0 A0,A1,B0; stage rest of buf1 tile t+1; mfma B0-quads
        RD_A(a0, 0, A0b); RD_A(a1, 1, A0b); RD_B(b0, 0, B0b);
        if (it) { ST_Bu1(0, t + 1, B1b); ST_Bu0(1, t + 1, B1b); ST_Bu1(1, t + 1, B1b); }
        FENCE; BARx; LGKM0;
        __builtin_amdgcn_s_setprio(1); QMM(0, 0, a0, b0); QMM(1, 0, a1, b0);
        __builtin_amdgcn_s_setprio(0); FENCE; BARx;

        // ph2: rd buf0 B1; stage buf0.{A0,A1,B0u0}(t+2); mfma B1-quads; vm3
        RD_B(b1, 1, B0b);
        ST_A(0, ts0, A0b); ST_A(1, ts0, A0b); ST_Bu0(0, ts0, B0b);
        FENCE; BARx; LGKM0;
        __builtin_amdgcn_s_setprio(1); QMM(0, 1, a0, b1); QMM(1, 1, a1, b1);
        __builtin_amdgcn_s_setprio(0); VM3; FENCE; BARx;

        // ph3: rd buf1 A0,A1,B0; stage buf0.{B0u1,B1u0,B1u1}(t+2); mfma
        RD_A(a0, 0, A1b); RD_A(a1, 1, A1b); RD_B(b0, 0, B1b);
        ST_Bu1(0, ts0, B0b); ST_Bu0(1, ts0, B0b); ST_Bu1(1, ts0, B0b);
        FENCE; BARx; LGKM0;
        __builtin_amdgcn_s_setprio(1); QMM(0, 0, a0, b0); QMM(1, 0, a1, b0);
        __builtin_amdgcn_s_setprio(0); FENCE; BARx;

        // ph4: rd buf1 B1; stage buf1.{A0,A1,B0u0}(t+3); mfma; vm3
        RD_B(b1, 1, B1b);
        ST_A(0, ts1, A1b); ST_A(1, ts1, A1b); ST_Bu0(0, ts1, B1b);
        FENCE; BARx; LGKM0;
        __builtin_amdgcn_s_setprio(1); QMM(0, 1, a0, b1); QMM(1, 1, a1, b1);
        __builtin_amdgcn_s_setprio(0); VM3; FENCE; BARx;
    }

    // C-write: C/D layout col=lane&15, row=(lane>>4)*4+reg  [m89/m91]
    const long c_col0 = n_blk + w4 * 64 + fr;
    const long c_row0 = m_blk + wg * 64 + (lane >> 4) * 4;
#pragma unroll
    for (int rf = 0; rf < 4; rf++)
#pragma unroll
        for (int r = 0; r < 4; r++) {
            const long row = c_row0 + rf * 16 + r;
#pragma unroll
            for (int cf = 0; cf < 4; cf++)
                storev(&C[row * N + c_col0 + cf * 16], acc[rf][cf][r] * scale);
        }
}

template <typename OutT>
__global__ __launch_bounds__(512)
void gemm8(const bf* __restrict__ A, const bf* __restrict__ B,
           OutT* __restrict__ C, int K, int N,
           long sA, long sB, long sC, float scale)
{
    __shared__ __align__(16) u16 lds[49152];   // 96 KiB
    gemm8_core(A + blockIdx.z * sA, B + blockIdx.z * sB, C + blockIdx.z * sC,
               K, N, blockIdx.y * 128, blockIdx.x * 256, scale, lds);
}

__global__ __launch_bounds__(512)
void gemm8_qk(const bf* __restrict__ xb, const bf* __restrict__ memb,
              const bf* __restrict__ Wqb, const bf* __restrict__ Wkb,
              bf* __restrict__ Q, bf* __restrict__ Kp, float qscale)
{
    __shared__ __align__(16) u16 lds[49152];
    const int z = blockIdx.z;
    gemm8_core(z ? memb : xb, z ? Wkb : Wqb, z ? Kp : Q, 1024, 1024,
               blockIdx.y * 128, blockIdx.x * 256, z ? 1.f : qscale, lds);
}

// ============================================================================
// fp32 -> bf16 conversion pre-pass (memory-bound, ~20 us total)
// ============================================================================
__global__ __launch_bounds__(256)
void cvt2(const float* __restrict__ a, const float* __restrict__ b,
          bf* __restrict__ da, bf* __restrict__ db, long n)
{
    const float* s = blockIdx.z ? b : a;
    bf* d = blockIdx.z ? db : da;
    const long stride = (long)gridDim.x * 256;
    for (long i = (long)blockIdx.x * 256 + threadIdx.x; i * 8 < n; i += stride)
        *(bf16x8*)(d + i * 8) = ld8f(s + i * 8);
}

__global__ __launch_bounds__(256)
void cvt_w(const float* __restrict__ w0, const float* __restrict__ w1,
           const float* __restrict__ w2, const float* __restrict__ w3,
           bf* __restrict__ d)
{
    const int z = blockIdx.z;
    const float* s = (z == 0) ? w0 : (z == 1) ? w1 : (z == 2) ? w2 : w3;
    bf* dz = d + (long)z * (1 << 20);
    const long i = ((long)blockIdx.x * 256 + threadIdx.x) * 8;
    *(bf16x8*)(dz + i) = ld8f(s + i);
}

// ============================================================================
// In-place bf16 row softmax over 2048 logits; one block per row.
// ============================================================================
__global__ __launch_bounds__(256)
void softmax_rows_2048(bf* __restrict__ X)
{
    const long row = blockIdx.x;
    const int t = threadIdx.x;
    const int wave = t >> 6, lane = t & 63;
    __shared__ float red[8];

    float v[8];
    float m = -1e30f;
#pragma unroll
    for (int i = 0; i < 8; i++) {
        v[i] = __bfloat162float(X[row * 2048 + t + i * 256]);
        m = fmaxf(m, v[i]);
    }
#pragma unroll
    for (int o = 32; o > 0; o >>= 1) m = fmaxf(m, __shfl_xor(m, o, 64));
    if (lane == 0) red[wave] = m;
    __syncthreads();
    m = fmaxf(fmaxf(red[0], red[1]), fmaxf(red[2], red[3]));

    float s = 0.f;
#pragma unroll
    for (int i = 0; i < 8; i++) { v[i] = __expf(v[i] - m); s += v[i]; }
#pragma unroll
    for (int o = 32; o > 0; o >>= 1) s += __shfl_xor(s, o, 64);
    if (lane == 0) red[4 + wave] = s;
    __syncthreads();
    s = red[4] + red[5] + red[6] + red[7];

    const float inv = 1.f / s;
#pragma unroll
    for (int i = 0; i < 8; i++)
        X[row * 2048 + t + i * 256] = __float2bfloat16(v[i] * inv);
}

// ============================================================================
// Pipeline (8 dispatches), all GEMMs 4-phase 128x256 (every grid >= 256 blk):
//   1. cvt2   x,mem -> xb,memb bf16 (in d_out, dead after logits)
//   2. cvt_w  weights -> bf16 (ws chunk 3)
//   3. qk     grid(4,64,2)=512
//   4. Vt     grid(8,8,4)=256     Vt[b][e,m] = Wvb[e,:].memb[b][m,:]
//   5. logits grid(8,16,4)=512 -> Lg bf16 [4][2048][2048] in d_out
//   6. softmax 8192 blk in place
//   7. AO     grid(4,16,4)=256 (aliases Q; K=2048)
//   8. final  grid(4,64,1)=256 -> out fp32
// Workspace: Q/AO 16 + Kp 16 + Vt 16 + Wb 8 = 56 MiB.
// ============================================================================
extern "C" void kernel_launch(void* const* d_in, const int* in_sizes, int n_in,
                              void* d_out, int out_size, void* d_ws, size_t ws_size,
                              hipStream_t stream)
{
    const float* x   = (const float*)d_in[0];
    const float* mem = (const float*)d_in[1];
    const float* Wq  = (const float*)d_in[2];
    const float* Wk  = (const float*)d_in[3];
    const float* Wv  = (const float*)d_in[4];
    const float* Wo  = (const float*)d_in[5];

    constexpr int  B = 4, L = 2048, D = 1024;
    constexpr long LD = (long)L * D;
    constexpr long LL = (long)L * L;
    constexpr size_t CH = 1u << 24;

    char* ws = (char*)d_ws;
    bf* Q   = (bf*)(ws + 0 * CH);
    bf* Kp  = (bf*)(ws + 1 * CH);
    bf* Vt  = (bf*)(ws + 2 * CH);
    bf* Wb  = (bf*)(ws + 3 * CH);
    bf* Wqb = Wb;
    bf* Wkb = Wb + (long)(1 << 20);
    bf* Wvb = Wb + (long)2 * (1 << 20);
    bf* Wob = Wb + (long)3 * (1 << 20);
    bf* AO  = Q;

    bf* xb   = (bf*)d_out;
    bf* memb = (bf*)d_out + B * LD;
    bf* Lg   = (bf*)d_out;

    const float qscale = 0.03125f;

    cvt2<<<dim3(1024, 1, 2), dim3(256), 0, stream>>>(x, mem, xb, memb, B * LD);
    cvt_w<<<dim3(512, 1, 4), dim3(256), 0, stream>>>(Wq, Wk, Wv, Wo, Wb);

    // 3. Q = x@Wq^T * s, K = mem@Wk^T : M=8192, N=1024, K=1024
    gemm8_qk<<<dim3(4, 64, 2), dim3(512), 0, stream>>>(
        xb, memb, Wqb, Wkb, Q, Kp, qscale);

    // 4. Vt[b] = Wvb (.) memb[b]^T : M=1024, N=2048, K=1024
    gemm8<bf><<<dim3(8, 8, 4), dim3(512), 0, stream>>>(
        Wvb, memb, Vt, D, L, 0, LD, (long)D * L, 1.f);

    // 5. logits[b][q,m] = Q[b][q,:].Kp[b][m,:] : M=2048, N=2048, K=1024
    gemm8<bf><<<dim3(8, 16, 4), dim3(512), 0, stream>>>(
        Q, Kp, Lg, D, L, LD, LD, LL, 1.f);

    // 6. softmax in place
    softmax_rows_2048<<<dim3(B * L), dim3(256), 0, stream>>>(Lg);

    // 7. AO[b][q,e] = P[b][q,:].Vt[b][e,:] : M=2048, N=1024, K=2048
    gemm8<bf><<<dim3(4, 16, 4), dim3(512), 0, stream>>>(
        Lg, Vt, AO, L, D, LL, (long)D * L, LD, 1.f);

    // 8. out = AO @ Wob^T : M=8192, N=1024, K=1024
    gemm8<float><<<dim3(4, 64, 1), dim3(512), 0, stream>>>(
        AO, Wob, (float*)d_out, D, D, 0, 0, 0, 1.f);
}

// Round 4
// 296.865 us; speedup vs baseline: 1.0120x; 1.0120x over previous
//
#include <hip/hip_runtime.h>
#include <hip/hip_bf16.h>

typedef unsigned short u16;
typedef __bf16 bf16x8 __attribute__((ext_vector_type(8)));
typedef float floatx4 __attribute__((ext_vector_type(4)));
typedef __hip_bfloat16 bf;

__device__ __forceinline__ __bf16 f2b(float f) {
    __hip_bfloat16 h = __float2bfloat16(f);
    return *reinterpret_cast<__bf16*>(&h);
}
__device__ __forceinline__ bf16x8 ld8f(const float* p) {
    float4 a = ((const float4*)p)[0];
    float4 b = ((const float4*)p)[1];
    bf16x8 r;
    r[0] = f2b(a.x); r[1] = f2b(a.y); r[2] = f2b(a.z); r[3] = f2b(a.w);
    r[4] = f2b(b.x); r[5] = f2b(b.y); r[6] = f2b(b.z); r[7] = f2b(b.w);
    return r;
}
__device__ __forceinline__ void storev(float* p, float v) { *p = v; }
__device__ __forceinline__ void storev(bf* p, float v)    { *p = __float2bfloat16(v); }

// async 16-B global->LDS (dest = wave-uniform base + lane*16; dest map tid*16
// conforms: wave*1024 + lane*16)
__device__ __forceinline__ void gl16(const bf* g, u16* l) {
    __builtin_amdgcn_global_load_lds(
        (const __attribute__((address_space(1))) void*)g,
        (__attribute__((address_space(3))) void*)l, 16, 0, 0);
}

// T1 bijective XCD swizzle (all our grids have nwg % 8 == 0): XCD x = lid%8
// gets the contiguous tile range [x*nwg/8, ...), decomposed x-fastest.
__device__ __forceinline__ void swz3(int& bx, int& by, int& bz) {
    const int nx = gridDim.x, ny = gridDim.y, nz = gridDim.z;
    const int lid = blockIdx.x + nx * (blockIdx.y + ny * blockIdx.z);
    const int cpx = (nx * ny * nz) >> 3;
    const int s = (lid & 7) * cpx + (lid >> 3);
    bx = s % nx;
    const int r = s / nx;
    by = r % ny;
    bz = r / ny;
}

#define FENCE asm volatile("" ::: "memory")
#define BARx  __builtin_amdgcn_s_barrier()
#define LGKM0 asm volatile("s_waitcnt lgkmcnt(0)" ::: "memory")
#define VM3   asm volatile("s_waitcnt vmcnt(3)" ::: "memory")
#define VM6   asm volatile("s_waitcnt vmcnt(6)" ::: "memory")
#define VM0   asm volatile("s_waitcnt vmcnt(0)" ::: "memory")

// ============================================================================
// Kernel A: 256x256-tile 8-phase NT GEMM (m201 geometry) — for GEMMs with
// >= 256 tiles of 256x256 (qk, logits).  Intensity BM*BN/(BM+BN) = 128 FLOP/B
// vs 85 for 128x256: R3 diagnosis showed the 128x256 kernel is staging-BW
// bound at ~8.6 TB/s consumed -> intensity is the lever, not the schedule.
//
// Geometry: BK=64, 512 thr = 8 waves (2M x 4N), wave out 128x64 (acc[8][4]).
// LDS 128 KiB: 2 buffers x {A:[256][64], B:[256][64]}, linear rows (gl16).
// Staging unit = 64 rows x 64 elems = 8 KB = one gl16 across 512 threads.
//
// 8 phases / 2 K-tiles (t->buf0, t+1->buf1), 16 MFMA/phase (one C-quadrant):
//   ph1: rd A.h0+B0 buf0 (12 ds) | stage[if it] buf1.Au1,Au3 (t+1) | Q(0,0)
//   ph2: rd B1 buf0 (4)          | stage buf0.Au0,Au2 (t+2)        | Q(0,1)
//   ph3: rd A.h1 buf0 (8)        | stage buf0.Bu0,Bu1 (t+2)        | Q(1,1)
//   ph4: (no reads)              | stage buf0.Bu2,Bu3 (t+2)        | Q(1,0) VM6
//   ph5-8: mirror on buf1 (stages: buf0.Au1,Au3(t+2) / buf1.Au0,Au2(t+3) /
//          buf1.Bu0,Bu1(t+3) / buf1.Bu2,Bu3(t+3)), VM6 at ph8.
// Hazards (verified): every region staged >= 1 phase after its last LDS read
// (A.h0 units last-read ph1/ph5, B ph2/ph6, A.h1 ph3/ph7).  FIFO drain at 2
// issues/phase: VM6@ph4 drains {prev ph6,7,8, ph1} = all of buf1's tile t+1
// before ph5 reads it; VM6@ph8 drains {ph2..ph5} = all of buf0's tile t+2
// before next ph1.  Steady state 6-14 loads in flight, never 0.
// Iter 0: ph1 stage skipped (prologue staged tiles 0,1; VM0-drained).
// Regs: b0 lives ph1->ph4 (ph4 reads nothing from LDS).
// LDS k-swizzle as proven (R2: SQ_LDS_BANK_CONFLICT = 0): source col
// pre-XOR'd with (row&7)<<3, gl16 dest linear, read col kl^((row&7)<<3).
// Requires K % 128 == 0.
// ============================================================================

#define ST_A2(u, kt, Ab) \
    gl16(Asrc + (long)((u) * 64) * K + (long)(kt) * 64, (Ab) + (u) * 4096 + tid * 8)
#define ST_B2(u, kt, Bb) \
    gl16(Bsrc + (long)((u) * 64) * K + (long)(kt) * 64, (Bb) + (u) * 4096 + tid * 8)

#define RD_A2(dst, h, Ab) do { _Pragma("unroll") \
    for (int q_ = 0; q_ < 4; q_++) { \
        const u16* p_ = (Ab) + (wg * 128 + (h) * 64 + q_ * 16 + fr) * 64; \
        dst[q_ * 2 + 0] = *(const bf16x8*)(p_ + kl0); \
        dst[q_ * 2 + 1] = *(const bf16x8*)(p_ + kl1); \
    } } while (0)

#define RD_B2(dst, c, Bb) do { _Pragma("unroll") \
    for (int j_ = 0; j_ < 2; j_++) { \
        const u16* p_ = (Bb) + (w4 * 64 + (c) * 32 + j_ * 16 + fr) * 64; \
        dst[j_ * 2 + 0] = *(const bf16x8*)(p_ + kl0); \
        dst[j_ * 2 + 1] = *(const bf16x8*)(p_ + kl1); \
    } } while (0)

#define QMM2(h, c, av, bv) do { _Pragma("unroll") \
    for (int q_ = 0; q_ < 4; q_++) _Pragma("unroll") \
    for (int j_ = 0; j_ < 2; j_++) _Pragma("unroll") \
    for (int kk_ = 0; kk_ < 2; kk_++) \
        acc[(h) * 4 + q_][(c) * 2 + j_] = __builtin_amdgcn_mfma_f32_16x16x32_bf16( \
            av[q_ * 2 + kk_], bv[j_ * 2 + kk_], acc[(h) * 4 + q_][(c) * 2 + j_], 0, 0, 0); \
} while (0)

template <typename OutT>
__device__ __forceinline__ void gemm256_core(
    const bf* __restrict__ A, const bf* __restrict__ B, OutT* __restrict__ C,
    int K, int N, int m_blk, int n_blk, float scale, u16* lds)
{
    const int tid = threadIdx.x;
    const int w = tid >> 6, lane = tid & 63;
    const int wg = w >> 2, w4 = w & 3;          // wave grid 2M x 4N
    const int fr = lane & 15, kg = lane >> 4;

    u16* const A0b = lds;                        // [256][64]
    u16* const B0b = lds + 16384;
    u16* const A1b = lds + 32768;
    u16* const B1b = lds + 49152;                // total 65536 elems = 128 KiB

    const int kl0 = (kg * 8) ^ ((fr & 7) << 3);
    const int kl1 = kl0 ^ 32;

    const int sr  = tid >> 3;                    // 0..63: row within 64-row unit
    const int scs = ((tid & 7) * 8) ^ ((sr & 7) << 3);
    const bf* Asrc = A + (long)(m_blk + sr) * K + scs;
    const bf* Bsrc = B + (long)(n_blk + sr) * K + scs;

    floatx4 acc[8][4];
#pragma unroll
    for (int i = 0; i < 8; i++)
#pragma unroll
        for (int j = 0; j < 4; j++) acc[i][j] = (floatx4){0.f, 0.f, 0.f, 0.f};

    bf16x8 a[8], b0[4], b1[4];

    const int T     = K >> 6;    // K-tiles, even
    const int iters = T >> 1;

    // prologue: tile0 -> buf0, tile1 -> buf1 (16 units); drain
#pragma unroll
    for (int u = 0; u < 4; u++) { ST_A2(u, 0, A0b); ST_B2(u, 0, B0b); }
#pragma unroll
    for (int u = 0; u < 4; u++) { ST_A2(u, 1, A1b); ST_B2(u, 1, B1b); }
    VM0; BARx;

    for (int it = 0; it < iters; ++it) {
        const int t   = it * 2;
        const int ts0 = (t + 2 < T) ? t + 2 : 0;   // clamped: garbage unused
        const int ts1 = (t + 3 < T) ? t + 3 : 0;

        // ph1
        RD_A2(a, 0, A0b); RD_B2(b0, 0, B0b);
        if (it) { ST_A2(1, t + 1, A1b); ST_A2(3, t + 1, A1b); }
        FENCE; BARx; LGKM0;
        __builtin_amdgcn_s_setprio(1); QMM2(0, 0, a, b0);
        __builtin_amdgcn_s_setprio(0); FENCE; BARx;

        // ph2
        RD_B2(b1, 1, B0b);
        ST_A2(0, ts0, A0b); ST_A2(2, ts0, A0b);
        FENCE; BARx; LGKM0;
        __builtin_amdgcn_s_setprio(1); QMM2(0, 1, a, b1);
        __builtin_amdgcn_s_setprio(0); FENCE; BARx;

        // ph3
        RD_A2(a, 1, A0b);
        ST_B2(0, ts0, B0b); ST_B2(1, ts0, B0b);
        FENCE; BARx; LGKM0;
        __builtin_amdgcn_s_setprio(1); QMM2(1, 1, a, b1);
        __builtin_amdgcn_s_setprio(0); FENCE; BARx;

        // ph4 (no ds reads; b0 from ph1, a from ph3)
        ST_B2(2, ts0, B0b); ST_B2(3, ts0, B0b);
        FENCE; BARx;
        __builtin_amdgcn_s_setprio(1); QMM2(1, 0, a, b0);
        __builtin_amdgcn_s_setprio(0); VM6; FENCE; BARx;

        // ph5
        RD_A2(a, 0, A1b); RD_B2(b0, 0, B1b);
        ST_A2(1, ts0, A0b); ST_A2(3, ts0, A0b);
        FENCE; BARx; LGKM0;
        __builtin_amdgcn_s_setprio(1); QMM2(0, 0, a, b0);
        __builtin_amdgcn_s_setprio(0); FENCE; BARx;

        // ph6
        RD_B2(b1, 1, B1b);
        ST_A2(0, ts1, A1b); ST_A2(2, ts1, A1b);
        FENCE; BARx; LGKM0;
        __builtin_amdgcn_s_setprio(1); QMM2(0, 1, a, b1);
        __builtin_amdgcn_s_setprio(0); FENCE; BARx;

        // ph7
        RD_A2(a, 1, A1b);
        ST_B2(0, ts1, B1b); ST_B2(1, ts1, B1b);
        FENCE; BARx; LGKM0;
        __builtin_amdgcn_s_setprio(1); QMM2(1, 1, a, b1);
        __builtin_amdgcn_s_setprio(0); FENCE; BARx;

        // ph8
        ST_B2(2, ts1, B1b); ST_B2(3, ts1, B1b);
        FENCE; BARx;
        __builtin_amdgcn_s_setprio(1); QMM2(1, 0, a, b0);
        __builtin_amdgcn_s_setprio(0); VM6; FENCE; BARx;
    }

    // C-write: col=lane&15, row=(lane>>4)*4+reg  [m89/m91]
    const long c_col0 = n_blk + w4 * 64 + fr;
    const long c_row0 = m_blk + wg * 128 + (lane >> 4) * 4;
#pragma unroll
    for (int rf = 0; rf < 8; rf++)
#pragma unroll
        for (int r = 0; r < 4; r++) {
            const long row = c_row0 + rf * 16 + r;
#pragma unroll
            for (int cf = 0; cf < 4; cf++)
                storev(&C[row * N + c_col0 + cf * 16], acc[rf][cf][r] * scale);
        }
}

template <typename OutT>
__global__ __launch_bounds__(512)
void gemm256(const bf* __restrict__ A, const bf* __restrict__ B,
             OutT* __restrict__ C, int K, int N,
             long sA, long sB, long sC, float scale)
{
    __shared__ __align__(16) u16 lds[65536];   // 128 KiB
    int bx, by, bz; swz3(bx, by, bz);
    gemm256_core(A + bz * sA, B + bz * sB, C + bz * sC,
                 K, N, by * 256, bx * 256, scale, lds);
}

__global__ __launch_bounds__(512)
void gemm256_qk(const bf* __restrict__ xb, const bf* __restrict__ memb,
                const bf* __restrict__ Wqb, const bf* __restrict__ Wkb,
                bf* __restrict__ Q, bf* __restrict__ Kp, float qscale)
{
    __shared__ __align__(16) u16 lds[65536];
    int bx, by, bz; swz3(bx, by, bz);
    gemm256_core(bz ? memb : xb, bz ? Wkb : Wqb, bz ? Kp : Q, 1024, 1024,
                 by * 256, bx * 256, bz ? 1.f : qscale, lds);
}

// ============================================================================
// Kernel B: 128x256-tile 4-phase NT GEMM (unchanged R3 core + XCD swizzle) —
// for GEMMs with < 256 tiles of 256x256 (Vt, AO, final: only 128 each).
// ============================================================================

#define ST_A(h, kt, Ab) \
    gl16(Asrc + (long)((h) * 32) * K + (long)(kt) * 64, (Ab) + (h) * 4096 + tid * 8)
#define ST_Bu0(c, kt, Bb) \
    gl16(Bsrc + (long)((c) * 32) * K + (long)(kt) * 64, (Bb) + (c) * 8192 + tid * 8)
#define ST_Bu1(c, kt, Bb) \
    gl16(Bsrc + (long)((c) * 32 + 128) * K + (long)(kt) * 64, (Bb) + (c) * 8192 + 4096 + tid * 8)

#define RD_A(dst, h, Ab) do { _Pragma("unroll") \
    for (int q_ = 0; q_ < 2; q_++) { \
        const u16* p_ = (Ab) + ((h) * 64 + wg * 32 + q_ * 16 + fr) * 64; \
        dst[q_ * 2 + 0] = *(const bf16x8*)(p_ + kl0); \
        dst[q_ * 2 + 1] = *(const bf16x8*)(p_ + kl1); \
    } } while (0)

#define RD_B(dst, c, Bb) do { _Pragma("unroll") \
    for (int j_ = 0; j_ < 2; j_++) { \
        const u16* p_ = (Bb) + ((c) * 128 + w4 * 32 + j_ * 16 + fr) * 64; \
        dst[j_ * 2 + 0] = *(const bf16x8*)(p_ + kl0); \
        dst[j_ * 2 + 1] = *(const bf16x8*)(p_ + kl1); \
    } } while (0)

#define QMM(h, c, av, bv) do { _Pragma("unroll") \
    for (int q_ = 0; q_ < 2; q_++) _Pragma("unroll") \
    for (int j_ = 0; j_ < 2; j_++) _Pragma("unroll") \
    for (int kk_ = 0; kk_ < 2; kk_++) \
        acc[(h) * 2 + q_][(c) * 2 + j_] = __builtin_amdgcn_mfma_f32_16x16x32_bf16( \
            av[q_ * 2 + kk_], bv[j_ * 2 + kk_], acc[(h) * 2 + q_][(c) * 2 + j_], 0, 0, 0); \
} while (0)

template <typename OutT>
__device__ __forceinline__ void gemm128_core(
    const bf* __restrict__ A, const bf* __restrict__ B, OutT* __restrict__ C,
    int K, int N, int m_blk, int n_blk, float scale, u16* lds)
{
    const int tid  = threadIdx.x;
    const int w    = tid >> 6, lane = tid & 63;
    const int wg   = w >> 2, w4 = w & 3;
    const int fr   = lane & 15, kg = lane >> 4;

    u16* const A0b = lds;
    u16* const B0b = lds + 8192;
    u16* const A1b = lds + 24576;
    u16* const B1b = lds + 32768;

    const int kl0 = (kg * 8) ^ ((fr & 7) << 3);
    const int kl1 = kl0 ^ 32;

    const int sr  = tid >> 3;
    const int scs = ((tid & 7) * 8) ^ ((sr & 7) << 3);
    const bf* Asrc = A + (long)(m_blk + (tid >> 8) * 64 + (sr & 31)) * K + scs;
    const bf* Bsrc = B + (long)(n_blk + (tid >> 8) * 64 + (sr & 31)) * K + scs;

    floatx4 acc[4][4];
#pragma unroll
    for (int i = 0; i < 4; i++)
#pragma unroll
        for (int j = 0; j < 4; j++) acc[i][j] = (floatx4){0.f, 0.f, 0.f, 0.f};

    bf16x8 a0[4], a1[4], b0[4], b1[4];

    const int T     = K >> 6;
    const int iters = T >> 1;

    ST_A(0, 0, A0b); ST_A(1, 0, A0b);
    ST_Bu0(0, 0, B0b); ST_Bu1(0, 0, B0b); ST_Bu0(1, 0, B0b); ST_Bu1(1, 0, B0b);
    ST_A(0, 1, A1b); ST_A(1, 1, A1b);
    ST_Bu0(0, 1, B1b); ST_Bu1(0, 1, B1b); ST_Bu0(1, 1, B1b); ST_Bu1(1, 1, B1b);
    VM0; BARx;

    for (int it = 0; it < iters; ++it) {
        const int t   = it * 2;
        const int ts0 = (t + 2 < T) ? t + 2 : 0;
        const int ts1 = (t + 3 < T) ? t + 3 : 0;

        RD_A(a0, 0, A0b); RD_A(a1, 1, A0b); RD_B(b0, 0, B0b);
        if (it) { ST_Bu1(0, t + 1, B1b); ST_Bu0(1, t + 1, B1b); ST_Bu1(1, t + 1, B1b); }
        FENCE; BARx; LGKM0;
        __builtin_amdgcn_s_setprio(1); QMM(0, 0, a0, b0); QMM(1, 0, a1, b0);
        __builtin_amdgcn_s_setprio(0); FENCE; BARx;

        RD_B(b1, 1, B0b);
        ST_A(0, ts0, A0b); ST_A(1, ts0, A0b); ST_Bu0(0, ts0, B0b);
        FENCE; BARx; LGKM0;
        __builtin_amdgcn_s_setprio(1); QMM(0, 1, a0, b1); QMM(1, 1, a1, b1);
        __builtin_amdgcn_s_setprio(0); VM3; FENCE; BARx;

        RD_A(a0, 0, A1b); RD_A(a1, 1, A1b); RD_B(b0, 0, B1b);
        ST_Bu1(0, ts0, B0b); ST_Bu0(1, ts0, B0b); ST_Bu1(1, ts0, B0b);
        FENCE; BARx; LGKM0;
        __builtin_amdgcn_s_setprio(1); QMM(0, 0, a0, b0); QMM(1, 0, a1, b0);
        __builtin_amdgcn_s_setprio(0); FENCE; BARx;

        RD_B(b1, 1, B1b);
        ST_A(0, ts1, A1b); ST_A(1, ts1, A1b); ST_Bu0(0, ts1, B1b);
        FENCE; BARx; LGKM0;
        __builtin_amdgcn_s_setprio(1); QMM(0, 1, a0, b1); QMM(1, 1, a1, b1);
        __builtin_amdgcn_s_setprio(0); VM3; FENCE; BARx;
    }

    const long c_col0 = n_blk + w4 * 64 + fr;
    const long c_row0 = m_blk + wg * 64 + (lane >> 4) * 4;
#pragma unroll
    for (int rf = 0; rf < 4; rf++)
#pragma unroll
        for (int r = 0; r < 4; r++) {
            const long row = c_row0 + rf * 16 + r;
#pragma unroll
            for (int cf = 0; cf < 4; cf++)
                storev(&C[row * N + c_col0 + cf * 16], acc[rf][cf][r] * scale);
        }
}

template <typename OutT>
__global__ __launch_bounds__(512)
void gemm128(const bf* __restrict__ A, const bf* __restrict__ B,
             OutT* __restrict__ C, int K, int N,
             long sA, long sB, long sC, float scale)
{
    __shared__ __align__(16) u16 lds[49152];   // 96 KiB
    int bx, by, bz; swz3(bx, by, bz);
    gemm128_core(A + bz * sA, B + bz * sB, C + bz * sC,
                 K, N, by * 128, bx * 256, scale, lds);
}

// ============================================================================
// fp32 -> bf16 conversion pre-pass
// ============================================================================
__global__ __launch_bounds__(256)
void cvt2(const float* __restrict__ a, const float* __restrict__ b,
          bf* __restrict__ da, bf* __restrict__ db, long n)
{
    const float* s = blockIdx.z ? b : a;
    bf* d = blockIdx.z ? db : da;
    const long stride = (long)gridDim.x * 256;
    for (long i = (long)blockIdx.x * 256 + threadIdx.x; i * 8 < n; i += stride)
        *(bf16x8*)(d + i * 8) = ld8f(s + i * 8);
}

__global__ __launch_bounds__(256)
void cvt_w(const float* __restrict__ w0, const float* __restrict__ w1,
           const float* __restrict__ w2, const float* __restrict__ w3,
           bf* __restrict__ d)
{
    const int z = blockIdx.z;
    const float* s = (z == 0) ? w0 : (z == 1) ? w1 : (z == 2) ? w2 : w3;
    bf* dz = d + (long)z * (1 << 20);
    const long i = ((long)blockIdx.x * 256 + threadIdx.x) * 8;
    *(bf16x8*)(dz + i) = ld8f(s + i);
}

// ============================================================================
// In-place bf16 row softmax over 2048 logits; one block per row.
// ============================================================================
__global__ __launch_bounds__(256)
void softmax_rows_2048(bf* __restrict__ X)
{
    const long row = blockIdx.x;
    const int t = threadIdx.x;
    const int wave = t >> 6, lane = t & 63;
    __shared__ float red[8];

    float v[8];
    float m = -1e30f;
#pragma unroll
    for (int i = 0; i < 8; i++) {
        v[i] = __bfloat162float(X[row * 2048 + t + i * 256]);
        m = fmaxf(m, v[i]);
    }
#pragma unroll
    for (int o = 32; o > 0; o >>= 1) m = fmaxf(m, __shfl_xor(m, o, 64));
    if (lane == 0) red[wave] = m;
    __syncthreads();
    m = fmaxf(fmaxf(red[0], red[1]), fmaxf(red[2], red[3]));

    float s = 0.f;
#pragma unroll
    for (int i = 0; i < 8; i++) { v[i] = __expf(v[i] - m); s += v[i]; }
#pragma unroll
    for (int o = 32; o > 0; o >>= 1) s += __shfl_xor(s, o, 64);
    if (lane == 0) red[4 + wave] = s;
    __syncthreads();
    s = red[4] + red[5] + red[6] + red[7];

    const float inv = 1.f / s;
#pragma unroll
    for (int i = 0; i < 8; i++)
        X[row * 2048 + t + i * 256] = __float2bfloat16(v[i] * inv);
}

// ============================================================================
// Pipeline (8 dispatches):
//   1. cvt2   x,mem -> xb,memb bf16 (in d_out, dead after logits)
//   2. cvt_w  weights -> bf16 (ws chunk 3)
//   3. qk     gemm256 grid(4,32,2)=256     M=8192,N=1024,K=1024
//   4. Vt     gemm128 grid(8,8,4)=256      M=1024,N=2048,K=1024
//   5. logits gemm256 grid(8,8,4)=256      M=N=2048,K=1024 -> Lg in d_out
//   6. softmax 8192 blk in place
//   7. AO     gemm128 grid(4,16,4)=256     M=2048,N=1024,K=2048 (aliases Q)
//   8. final  gemm128 grid(4,64,1)=256     M=8192,N=1024,K=1024 -> out fp32
// Workspace: Q/AO 16 + Kp 16 + Vt 16 + Wb 8 = 56 MiB.
// ============================================================================
extern "C" void kernel_launch(void* const* d_in, const int* in_sizes, int n_in,
                              void* d_out, int out_size, void* d_ws, size_t ws_size,
                              hipStream_t stream)
{
    const float* x   = (const float*)d_in[0];
    const float* mem = (const float*)d_in[1];
    const float* Wq  = (const float*)d_in[2];
    const float* Wk  = (const float*)d_in[3];
    const float* Wv  = (const float*)d_in[4];
    const float* Wo  = (const float*)d_in[5];

    constexpr int  B = 4, L = 2048, D = 1024;
    constexpr long LD = (long)L * D;
    constexpr long LL = (long)L * L;
    constexpr size_t CH = 1u << 24;

    char* ws = (char*)d_ws;
    bf* Q   = (bf*)(ws + 0 * CH);
    bf* Kp  = (bf*)(ws + 1 * CH);
    bf* Vt  = (bf*)(ws + 2 * CH);
    bf* Wb  = (bf*)(ws + 3 * CH);
    bf* Wqb = Wb;
    bf* Wkb = Wb + (long)(1 << 20);
    bf* Wvb = Wb + (long)2 * (1 << 20);
    bf* Wob = Wb + (long)3 * (1 << 20);
    bf* AO  = Q;

    bf* xb   = (bf*)d_out;
    bf* memb = (bf*)d_out + B * LD;
    bf* Lg   = (bf*)d_out;

    const float qscale = 0.03125f;

    cvt2<<<dim3(1024, 1, 2), dim3(256), 0, stream>>>(x, mem, xb, memb, B * LD);
    cvt_w<<<dim3(512, 1, 4), dim3(256), 0, stream>>>(Wq, Wk, Wv, Wo, Wb);

    // 3. Q = x@Wq^T * s, K = mem@Wk^T : M=8192, N=1024, K=1024 (256x256 tiles)
    gemm256_qk<<<dim3(4, 32, 2), dim3(512), 0, stream>>>(
        xb, memb, Wqb, Wkb, Q, Kp, qscale);

    // 4. Vt[b] = Wvb (.) memb[b]^T : M=1024, N=2048, K=1024 (128x256 tiles)
    gemm128<bf><<<dim3(8, 8, 4), dim3(512), 0, stream>>>(
        Wvb, memb, Vt, D, L, 0, LD, (long)D * L, 1.f);

    // 5. logits[b][q,m] = Q[b][q,:].Kp[b][m,:] : M=N=2048, K=1024 (256x256)
    gemm256<bf><<<dim3(8, 8, 4), dim3(512), 0, stream>>>(
        Q, Kp, Lg, D, L, LD, LD, LL, 1.f);

    // 6. softmax in place
    softmax_rows_2048<<<dim3(B * L), dim3(256), 0, stream>>>(Lg);

    // 7. AO[b][q,e] = P[b][q,:].Vt[b][e,:] : M=2048, N=1024, K=2048 (128x256)
    gemm128<bf><<<dim3(4, 16, 4), dim3(512), 0, stream>>>(
        Lg, Vt, AO, L, D, LL, (long)D * L, LD, 1.f);

    // 8. out = AO @ Wob^T : M=8192, N=1024, K=1024 (128x256)
    gemm128<float><<<dim3(4, 64, 1), dim3(512), 0, stream>>>(
        AO, Wob, (float*)d_out, D, D, 0, 0, 0, 1.f);
}

// Round 5
// 285.264 us; speedup vs baseline: 1.0531x; 1.0407x over previous
//
#include <hip/hip_runtime.h>
#include <hip/hip_bf16.h>

typedef unsigned short u16;
typedef __bf16 bf16x8 __attribute__((ext_vector_type(8)));
typedef float floatx4 __attribute__((ext_vector_type(4)));
typedef __hip_bfloat16 bf;

__device__ __forceinline__ __bf16 f2b(float f) {
    __hip_bfloat16 h = __float2bfloat16(f);
    return *reinterpret_cast<__bf16*>(&h);
}
__device__ __forceinline__ bf16x8 ld8f(const float* p) {
    float4 a = ((const float4*)p)[0];
    float4 b = ((const float4*)p)[1];
    bf16x8 r;
    r[0] = f2b(a.x); r[1] = f2b(a.y); r[2] = f2b(a.z); r[3] = f2b(a.w);
    r[4] = f2b(b.x); r[5] = f2b(b.y); r[6] = f2b(b.z); r[7] = f2b(b.w);
    return r;
}
__device__ __forceinline__ void storev(float* p, float v) { *p = v; }
__device__ __forceinline__ void storev(bf* p, float v)    { *p = __float2bfloat16(v); }

// async 16-B global->LDS (dest = wave-uniform base + lane*16; dest map tid*16
// conforms: wave*1024 + lane*16)
__device__ __forceinline__ void gl16(const bf* g, u16* l) {
    __builtin_amdgcn_global_load_lds(
        (const __attribute__((address_space(1))) void*)g,
        (__attribute__((address_space(3))) void*)l, 16, 0, 0);
}

// T1 bijective XCD swizzle (all our grids have nwg % 8 == 0)
__device__ __forceinline__ void swz3(int& bx, int& by, int& bz) {
    const int nx = gridDim.x, ny = gridDim.y, nz = gridDim.z;
    const int lid = blockIdx.x + nx * (blockIdx.y + ny * blockIdx.z);
    const int cpx = (nx * ny * nz) >> 3;
    const int s = (lid & 7) * cpx + (lid >> 3);
    bx = s % nx;
    const int r = s / nx;
    by = r % ny;
    bz = r / ny;
}

#define FENCE asm volatile("" ::: "memory")
#define BARx  __builtin_amdgcn_s_barrier()
#define VM3   asm volatile("s_waitcnt vmcnt(3)" ::: "memory")
#define VM6   asm volatile("s_waitcnt vmcnt(6)" ::: "memory")
#define VM0   asm volatile("s_waitcnt vmcnt(0)" ::: "memory")
#define SP1   __builtin_amdgcn_s_setprio(1)
#define SP0   __builtin_amdgcn_s_setprio(0)

// ============================================================================
// R5 change (both GEMM cores): ONE barrier per phase, NO full lgkmcnt(0).
// R4 diagnosis: entry-barrier + lgkm full-drain serialized {ds_read | MFMA}
// pipes (phase = reads 384-1152cyc + MFMA 621cyc + overhead, serial ->
// MfmaUtil 26%).  Safety of the single-barrier form, region-by-region:
//   - every ds_read issued in phase p is CONSUMED by phase p's MFMA, so the
//     compiler's counted lgkm wait completes it before the exit barrier;
//   - staging that overwrites a region last-read at phase p is issued only
//     after phase p's exit barrier (same staircase as R4, +1 phase gap);
//   - vmcnt drains (VM6@ph4/ph8, VM3@ph2/ph4) sit before their exit barrier,
//     so [own VM + barrier] still proves all waves' gl16s landed before any
//     wave reads the freshly staged buffer.  Drain arithmetic unchanged.
// Compiler now interleaves {reads | gl16 | MFMA} inside the phase window
// with precise counted waits (m97: it emits lgkmcnt(4/3/1/0) fine-grained).
// ============================================================================

// ---------------- Kernel A: 256x256 tile, BK=64, 8 phases / 2 K-tiles ------

#define ST_A2(u, kt, Ab) \
    gl16(Asrc + (long)((u) * 64) * K + (long)(kt) * 64, (Ab) + (u) * 4096 + tid * 8)
#define ST_B2(u, kt, Bb) \
    gl16(Bsrc + (long)((u) * 64) * K + (long)(kt) * 64, (Bb) + (u) * 4096 + tid * 8)

#define RD_A2(dst, h, Ab) do { _Pragma("unroll") \
    for (int q_ = 0; q_ < 4; q_++) { \
        const u16* p_ = (Ab) + (wg * 128 + (h) * 64 + q_ * 16 + fr) * 64; \
        dst[q_ * 2 + 0] = *(const bf16x8*)(p_ + kl0); \
        dst[q_ * 2 + 1] = *(const bf16x8*)(p_ + kl1); \
    } } while (0)

#define RD_B2(dst, c, Bb) do { _Pragma("unroll") \
    for (int j_ = 0; j_ < 2; j_++) { \
        const u16* p_ = (Bb) + (w4 * 64 + (c) * 32 + j_ * 16 + fr) * 64; \
        dst[j_ * 2 + 0] = *(const bf16x8*)(p_ + kl0); \
        dst[j_ * 2 + 1] = *(const bf16x8*)(p_ + kl1); \
    } } while (0)

#define QMM2(h, c, av, bv) do { _Pragma("unroll") \
    for (int q_ = 0; q_ < 4; q_++) _Pragma("unroll") \
    for (int j_ = 0; j_ < 2; j_++) _Pragma("unroll") \
    for (int kk_ = 0; kk_ < 2; kk_++) \
        acc[(h) * 4 + q_][(c) * 2 + j_] = __builtin_amdgcn_mfma_f32_16x16x32_bf16( \
            av[q_ * 2 + kk_], bv[j_ * 2 + kk_], acc[(h) * 4 + q_][(c) * 2 + j_], 0, 0, 0); \
} while (0)

template <typename OutT>
__device__ __forceinline__ void gemm256_core(
    const bf* __restrict__ A, const bf* __restrict__ B, OutT* __restrict__ C,
    int K, int N, int m_blk, int n_blk, float scale, u16* lds)
{
    const int tid = threadIdx.x;
    const int w = tid >> 6, lane = tid & 63;
    const int wg = w >> 2, w4 = w & 3;          // wave grid 2M x 4N
    const int fr = lane & 15, kg = lane >> 4;

    u16* const A0b = lds;                        // [256][64]
    u16* const B0b = lds + 16384;
    u16* const A1b = lds + 32768;
    u16* const B1b = lds + 49152;                // 65536 elems = 128 KiB

    const int kl0 = (kg * 8) ^ ((fr & 7) << 3);
    const int kl1 = kl0 ^ 32;

    const int sr  = tid >> 3;                    // 0..63: row within 64-row unit
    const int scs = ((tid & 7) * 8) ^ ((sr & 7) << 3);
    const bf* Asrc = A + (long)(m_blk + sr) * K + scs;
    const bf* Bsrc = B + (long)(n_blk + sr) * K + scs;

    floatx4 acc[8][4];
#pragma unroll
    for (int i = 0; i < 8; i++)
#pragma unroll
        for (int j = 0; j < 4; j++) acc[i][j] = (floatx4){0.f, 0.f, 0.f, 0.f};

    bf16x8 a[8], b0[4], b1[4];

    const int T     = K >> 6;    // K-tiles, even
    const int iters = T >> 1;

    // prologue: tile0 -> buf0, tile1 -> buf1 (16 units); drain
#pragma unroll
    for (int u = 0; u < 4; u++) { ST_A2(u, 0, A0b); ST_B2(u, 0, B0b); }
#pragma unroll
    for (int u = 0; u < 4; u++) { ST_A2(u, 1, A1b); ST_B2(u, 1, B1b); }
    VM0; BARx; FENCE;

    for (int it = 0; it < iters; ++it) {
        const int t   = it * 2;
        const int ts0 = (t + 2 < T) ? t + 2 : 0;   // clamped: garbage unused
        const int ts1 = (t + 3 < T) ? t + 3 : 0;

        // ph1: 12 rd, Q(0,0)
        RD_A2(a, 0, A0b); RD_B2(b0, 0, B0b);
        if (it) { ST_A2(1, t + 1, A1b); ST_A2(3, t + 1, A1b); }
        SP1; QMM2(0, 0, a, b0); SP0;
        FENCE; BARx; FENCE;

        // ph2: 4 rd, Q(0,1)
        RD_B2(b1, 1, B0b);
        ST_A2(0, ts0, A0b); ST_A2(2, ts0, A0b);
        SP1; QMM2(0, 1, a, b1); SP0;
        FENCE; BARx; FENCE;

        // ph3: 8 rd, Q(1,1)
        RD_A2(a, 1, A0b);
        ST_B2(0, ts0, B0b); ST_B2(1, ts0, B0b);
        SP1; QMM2(1, 1, a, b1); SP0;
        FENCE; BARx; FENCE;

        // ph4: 0 rd, Q(1,0); drain buf1 tile t+1 (8 oldest of 14)
        ST_B2(2, ts0, B0b); ST_B2(3, ts0, B0b);
        SP1; QMM2(1, 0, a, b0); SP0;
        VM6; BARx; FENCE;

        // ph5
        RD_A2(a, 0, A1b); RD_B2(b0, 0, B1b);
        ST_A2(1, ts0, A0b); ST_A2(3, ts0, A0b);
        SP1; QMM2(0, 0, a, b0); SP0;
        FENCE; BARx; FENCE;

        // ph6
        RD_B2(b1, 1, B1b);
        ST_A2(0, ts1, A1b); ST_A2(2, ts1, A1b);
        SP1; QMM2(0, 1, a, b1); SP0;
        FENCE; BARx; FENCE;

        // ph7
        RD_A2(a, 1, A1b);
        ST_B2(0, ts1, B1b); ST_B2(1, ts1, B1b);
        SP1; QMM2(1, 1, a, b1); SP0;
        FENCE; BARx; FENCE;

        // ph8: drain buf0 tile t+2
        ST_B2(2, ts1, B1b); ST_B2(3, ts1, B1b);
        SP1; QMM2(1, 0, a, b0); SP0;
        VM6; BARx; FENCE;
    }

    // C-write: col=lane&15, row=(lane>>4)*4+reg  [m89/m91]
    const long c_col0 = n_blk + w4 * 64 + fr;
    const long c_row0 = m_blk + wg * 128 + (lane >> 4) * 4;
#pragma unroll
    for (int rf = 0; rf < 8; rf++)
#pragma unroll
        for (int r = 0; r < 4; r++) {
            const long row = c_row0 + rf * 16 + r;
#pragma unroll
            for (int cf = 0; cf < 4; cf++)
                storev(&C[row * N + c_col0 + cf * 16], acc[rf][cf][r] * scale);
        }
}

template <typename OutT>
__global__ __launch_bounds__(512)
void gemm256(const bf* __restrict__ A, const bf* __restrict__ B,
             OutT* __restrict__ C, int K, int N,
             long sA, long sB, long sC, float scale)
{
    __shared__ __align__(16) u16 lds[65536];   // 128 KiB
    int bx, by, bz; swz3(bx, by, bz);
    gemm256_core(A + bz * sA, B + bz * sB, C + bz * sC,
                 K, N, by * 256, bx * 256, scale, lds);
}

__global__ __launch_bounds__(512)
void gemm256_qk(const bf* __restrict__ xb, const bf* __restrict__ memb,
                const bf* __restrict__ Wqb, const bf* __restrict__ Wkb,
                bf* __restrict__ Q, bf* __restrict__ Kp, float qscale)
{
    __shared__ __align__(16) u16 lds[65536];
    int bx, by, bz; swz3(bx, by, bz);
    gemm256_core(bz ? memb : xb, bz ? Wkb : Wqb, bz ? Kp : Q, 1024, 1024,
                 by * 256, bx * 256, bz ? 1.f : qscale, lds);
}

// ---------------- Kernel B: 128x256 tile, BK=64, 4 phases / 2 K-tiles ------

#define ST_A(h, kt, Ab) \
    gl16(Asrc + (long)((h) * 32) * K + (long)(kt) * 64, (Ab) + (h) * 4096 + tid * 8)
#define ST_Bu0(c, kt, Bb) \
    gl16(Bsrc + (long)((c) * 32) * K + (long)(kt) * 64, (Bb) + (c) * 8192 + tid * 8)
#define ST_Bu1(c, kt, Bb) \
    gl16(Bsrc + (long)((c) * 32 + 128) * K + (long)(kt) * 64, (Bb) + (c) * 8192 + 4096 + tid * 8)

#define RD_A(dst, h, Ab) do { _Pragma("unroll") \
    for (int q_ = 0; q_ < 2; q_++) { \
        const u16* p_ = (Ab) + ((h) * 64 + wg * 32 + q_ * 16 + fr) * 64; \
        dst[q_ * 2 + 0] = *(const bf16x8*)(p_ + kl0); \
        dst[q_ * 2 + 1] = *(const bf16x8*)(p_ + kl1); \
    } } while (0)

#define RD_B(dst, c, Bb) do { _Pragma("unroll") \
    for (int j_ = 0; j_ < 2; j_++) { \
        const u16* p_ = (Bb) + ((c) * 128 + w4 * 32 + j_ * 16 + fr) * 64; \
        dst[j_ * 2 + 0] = *(const bf16x8*)(p_ + kl0); \
        dst[j_ * 2 + 1] = *(const bf16x8*)(p_ + kl1); \
    } } while (0)

#define QMM(h, c, av, bv) do { _Pragma("unroll") \
    for (int q_ = 0; q_ < 2; q_++) _Pragma("unroll") \
    for (int j_ = 0; j_ < 2; j_++) _Pragma("unroll") \
    for (int kk_ = 0; kk_ < 2; kk_++) \
        acc[(h) * 2 + q_][(c) * 2 + j_] = __builtin_amdgcn_mfma_f32_16x16x32_bf16( \
            av[q_ * 2 + kk_], bv[j_ * 2 + kk_], acc[(h) * 2 + q_][(c) * 2 + j_], 0, 0, 0); \
} while (0)

template <typename OutT>
__device__ __forceinline__ void gemm128_core(
    const bf* __restrict__ A, const bf* __restrict__ B, OutT* __restrict__ C,
    int K, int N, int m_blk, int n_blk, float scale, u16* lds)
{
    const int tid  = threadIdx.x;
    const int w    = tid >> 6, lane = tid & 63;
    const int wg   = w >> 2, w4 = w & 3;
    const int fr   = lane & 15, kg = lane >> 4;

    u16* const A0b = lds;
    u16* const B0b = lds + 8192;
    u16* const A1b = lds + 24576;
    u16* const B1b = lds + 32768;

    const int kl0 = (kg * 8) ^ ((fr & 7) << 3);
    const int kl1 = kl0 ^ 32;

    const int sr  = tid >> 3;
    const int scs = ((tid & 7) * 8) ^ ((sr & 7) << 3);
    const bf* Asrc = A + (long)(m_blk + (tid >> 8) * 64 + (sr & 31)) * K + scs;
    const bf* Bsrc = B + (long)(n_blk + (tid >> 8) * 64 + (sr & 31)) * K + scs;

    floatx4 acc[4][4];
#pragma unroll
    for (int i = 0; i < 4; i++)
#pragma unroll
        for (int j = 0; j < 4; j++) acc[i][j] = (floatx4){0.f, 0.f, 0.f, 0.f};

    bf16x8 a0[4], a1[4], b0[4], b1[4];

    const int T     = K >> 6;
    const int iters = T >> 1;

    ST_A(0, 0, A0b); ST_A(1, 0, A0b);
    ST_Bu0(0, 0, B0b); ST_Bu1(0, 0, B0b); ST_Bu0(1, 0, B0b); ST_Bu1(1, 0, B0b);
    ST_A(0, 1, A1b); ST_A(1, 1, A1b);
    ST_Bu0(0, 1, B1b); ST_Bu1(0, 1, B1b); ST_Bu0(1, 1, B1b); ST_Bu1(1, 1, B1b);
    VM0; BARx; FENCE;

    for (int it = 0; it < iters; ++it) {
        const int t   = it * 2;
        const int ts0 = (t + 2 < T) ? t + 2 : 0;
        const int ts1 = (t + 3 < T) ? t + 3 : 0;

        // ph1
        RD_A(a0, 0, A0b); RD_A(a1, 1, A0b); RD_B(b0, 0, B0b);
        if (it) { ST_Bu1(0, t + 1, B1b); ST_Bu0(1, t + 1, B1b); ST_Bu1(1, t + 1, B1b); }
        SP1; QMM(0, 0, a0, b0); QMM(1, 0, a1, b0); SP0;
        FENCE; BARx; FENCE;

        // ph2: drain buf1 tile t+1
        RD_B(b1, 1, B0b);
        ST_A(0, ts0, A0b); ST_A(1, ts0, A0b); ST_Bu0(0, ts0, B0b);
        SP1; QMM(0, 1, a0, b1); QMM(1, 1, a1, b1); SP0;
        VM3; BARx; FENCE;

        // ph3
        RD_A(a0, 0, A1b); RD_A(a1, 1, A1b); RD_B(b0, 0, B1b);
        ST_Bu1(0, ts0, B0b); ST_Bu0(1, ts0, B0b); ST_Bu1(1, ts0, B0b);
        SP1; QMM(0, 0, a0, b0); QMM(1, 0, a1, b0); SP0;
        FENCE; BARx; FENCE;

        // ph4: drain buf0 tile t+2
        RD_B(b1, 1, B1b);
        ST_A(0, ts1, A1b); ST_A(1, ts1, A1b); ST_Bu0(0, ts1, B1b);
        SP1; QMM(0, 1, a0, b1); QMM(1, 1, a1, b1); SP0;
        VM3; BARx; FENCE;
    }

    const long c_col0 = n_blk + w4 * 64 + fr;
    const long c_row0 = m_blk + wg * 64 + (lane >> 4) * 4;
#pragma unroll
    for (int rf = 0; rf < 4; rf++)
#pragma unroll
        for (int r = 0; r < 4; r++) {
            const long row = c_row0 + rf * 16 + r;
#pragma unroll
            for (int cf = 0; cf < 4; cf++)
                storev(&C[row * N + c_col0 + cf * 16], acc[rf][cf][r] * scale);
        }
}

template <typename OutT>
__global__ __launch_bounds__(512)
void gemm128(const bf* __restrict__ A, const bf* __restrict__ B,
             OutT* __restrict__ C, int K, int N,
             long sA, long sB, long sC, float scale)
{
    __shared__ __align__(16) u16 lds[49152];   // 96 KiB
    int bx, by, bz; swz3(bx, by, bz);
    gemm128_core(A + bz * sA, B + bz * sB, C + bz * sC,
                 K, N, by * 128, bx * 256, scale, lds);
}

// ============================================================================
// fp32 -> bf16 conversion pre-pass
// ============================================================================
__global__ __launch_bounds__(256)
void cvt2(const float* __restrict__ a, const float* __restrict__ b,
          bf* __restrict__ da, bf* __restrict__ db, long n)
{
    const float* s = blockIdx.z ? b : a;
    bf* d = blockIdx.z ? db : da;
    const long stride = (long)gridDim.x * 256;
    for (long i = (long)blockIdx.x * 256 + threadIdx.x; i * 8 < n; i += stride)
        *(bf16x8*)(d + i * 8) = ld8f(s + i * 8);
}

__global__ __launch_bounds__(256)
void cvt_w(const float* __restrict__ w0, const float* __restrict__ w1,
           const float* __restrict__ w2, const float* __restrict__ w3,
           bf* __restrict__ d)
{
    const int z = blockIdx.z;
    const float* s = (z == 0) ? w0 : (z == 1) ? w1 : (z == 2) ? w2 : w3;
    bf* dz = d + (long)z * (1 << 20);
    const long i = ((long)blockIdx.x * 256 + threadIdx.x) * 8;
    *(bf16x8*)(dz + i) = ld8f(s + i);
}

// ============================================================================
// In-place bf16 row softmax over 2048 logits; one block per row.
// ============================================================================
__global__ __launch_bounds__(256)
void softmax_rows_2048(bf* __restrict__ X)
{
    const long row = blockIdx.x;
    const int t = threadIdx.x;
    const int wave = t >> 6, lane = t & 63;
    __shared__ float red[8];

    float v[8];
    float m = -1e30f;
#pragma unroll
    for (int i = 0; i < 8; i++) {
        v[i] = __bfloat162float(X[row * 2048 + t + i * 256]);
        m = fmaxf(m, v[i]);
    }
#pragma unroll
    for (int o = 32; o > 0; o >>= 1) m = fmaxf(m, __shfl_xor(m, o, 64));
    if (lane == 0) red[wave] = m;
    __syncthreads();
    m = fmaxf(fmaxf(red[0], red[1]), fmaxf(red[2], red[3]));

    float s = 0.f;
#pragma unroll
    for (int i = 0; i < 8; i++) { v[i] = __expf(v[i] - m); s += v[i]; }
#pragma unroll
    for (int o = 32; o > 0; o >>= 1) s += __shfl_xor(s, o, 64);
    if (lane == 0) red[4 + wave] = s;
    __syncthreads();
    s = red[4] + red[5] + red[6] + red[7];

    const float inv = 1.f / s;
#pragma unroll
    for (int i = 0; i < 8; i++)
        X[row * 2048 + t + i * 256] = __float2bfloat16(v[i] * inv);
}

// ============================================================================
// Pipeline (8 dispatches):
//   1. cvt2   x,mem -> xb,memb bf16 (in d_out, dead after logits)
//   2. cvt_w  weights -> bf16 (ws chunk 3)
//   3. qk     gemm256 grid(4,32,2)=256     M=8192,N=1024,K=1024
//   4. Vt     gemm128 grid(8,8,4)=256      M=1024,N=2048,K=1024
//   5. logits gemm256 grid(8,8,4)=256      M=N=2048,K=1024 -> Lg in d_out
//   6. softmax 8192 blk in place
//   7. AO     gemm128 grid(4,16,4)=256     M=2048,N=1024,K=2048 (aliases Q)
//   8. final  gemm128 grid(4,64,1)=256     M=8192,N=1024,K=1024 -> out fp32
// Workspace: Q/AO 16 + Kp 16 + Vt 16 + Wb 8 = 56 MiB.
// ============================================================================
extern "C" void kernel_launch(void* const* d_in, const int* in_sizes, int n_in,
                              void* d_out, int out_size, void* d_ws, size_t ws_size,
                              hipStream_t stream)
{
    const float* x   = (const float*)d_in[0];
    const float* mem = (const float*)d_in[1];
    const float* Wq  = (const float*)d_in[2];
    const float* Wk  = (const float*)d_in[3];
    const float* Wv  = (const float*)d_in[4];
    const float* Wo  = (const float*)d_in[5];

    constexpr int  B = 4, L = 2048, D = 1024;
    constexpr long LD = (long)L * D;
    constexpr long LL = (long)L * L;
    constexpr size_t CH = 1u << 24;

    char* ws = (char*)d_ws;
    bf* Q   = (bf*)(ws + 0 * CH);
    bf* Kp  = (bf*)(ws + 1 * CH);
    bf* Vt  = (bf*)(ws + 2 * CH);
    bf* Wb  = (bf*)(ws + 3 * CH);
    bf* Wqb = Wb;
    bf* Wkb = Wb + (long)(1 << 20);
    bf* Wvb = Wb + (long)2 * (1 << 20);
    bf* Wob = Wb + (long)3 * (1 << 20);
    bf* AO  = Q;

    bf* xb   = (bf*)d_out;
    bf* memb = (bf*)d_out + B * LD;
    bf* Lg   = (bf*)d_out;

    const float qscale = 0.03125f;

    cvt2<<<dim3(1024, 1, 2), dim3(256), 0, stream>>>(x, mem, xb, memb, B * LD);
    cvt_w<<<dim3(512, 1, 4), dim3(256), 0, stream>>>(Wq, Wk, Wv, Wo, Wb);

    // 3. Q = x@Wq^T * s, K = mem@Wk^T : M=8192, N=1024, K=1024 (256x256 tiles)
    gemm256_qk<<<dim3(4, 32, 2), dim3(512), 0, stream>>>(
        xb, memb, Wqb, Wkb, Q, Kp, qscale);

    // 4. Vt[b] = Wvb (.) memb[b]^T : M=1024, N=2048, K=1024 (128x256 tiles)
    gemm128<bf><<<dim3(8, 8, 4), dim3(512), 0, stream>>>(
        Wvb, memb, Vt, D, L, 0, LD, (long)D * L, 1.f);

    // 5. logits[b][q,m] = Q[b][q,:].Kp[b][m,:] : M=N=2048, K=1024 (256x256)
    gemm256<bf><<<dim3(8, 8, 4), dim3(512), 0, stream>>>(
        Q, Kp, Lg, D, L, LD, LD, LL, 1.f);

    // 6. softmax in place
    softmax_rows_2048<<<dim3(B * L), dim3(256), 0, stream>>>(Lg);

    // 7. AO[b][q,e] = P[b][q,:].Vt[b][e,:] : M=2048, N=1024, K=2048 (128x256)
    gemm128<bf><<<dim3(4, 16, 4), dim3(512), 0, stream>>>(
        Lg, Vt, AO, L, D, LL, (long)D * L, LD, 1.f);

    // 8. out = AO @ Wob^T : M=8192, N=1024, K=1024 (128x256)
    gemm128<float><<<dim3(4, 64, 1), dim3(512), 0, stream>>>(
        AO, Wob, (float*)d_out, D, D, 0, 0, 0, 1.f);
}